// Round 1
// baseline (350.690 us; speedup 1.0000x reference)
//
#include <hip/hip_runtime.h>
#include <math.h>

namespace {
constexpr int N_ = 16, L_ = 256, S_ = 128, E_ = 128, A_ = 9, D_ = 768, H_ = 768, RO_ = 24;
constexpr int IDXW = 130;       // S+2
constexpr int W1R = 6 * D_;     // 4608
constexpr float INV_SQRT_D = 0.03608439182435161f; // 1/sqrt(768)
} // namespace

using bshort8 = __attribute__((ext_vector_type(8))) short;
using f32x4v = __attribute__((ext_vector_type(4))) float;

__device__ __forceinline__ unsigned short f2bf(float f) {
    unsigned u = __builtin_bit_cast(unsigned, f);
    return (unsigned short)((u + 0x7fffu + ((u >> 16) & 1u)) >> 16);
}

// ---- zero Pe / Pa for atomic accumulation in mfma_mlp ----
__global__ __launch_bounds__(256) void zero2_k(float* __restrict__ Pe, float* __restrict__ Pa) {
    const int i = blockIdx.x * 256 + threadIdx.x;
    const float4 z = {0.f, 0.f, 0.f, 0.f};
    if (i < (N_ * E_ * H_) / 4) reinterpret_cast<float4*>(Pe)[i] = z;
    if (i < (N_ * A_ * H_) / 4) reinterpret_cast<float4*>(Pa)[i] = z;
}

// ---- gather + transpose + bf16: sentT[n][d][s] = all_emb[n][idx[s]][d] ----
__global__ __launch_bounds__(256) void gatherT_k(const float* __restrict__ all_emb,
                                                 const int* __restrict__ idxs,
                                                 unsigned short* __restrict__ sentT) {
    const int n = blockIdx.x, d0 = blockIdx.y * 64;
    __shared__ unsigned short tile[64][132];
#pragma unroll
    for (int it = 0; it < 8; ++it) {
        const int lin = threadIdx.x + 256 * it;      // 2048 float4 chunks
        const int s = lin >> 4, dq = (lin & 15) * 4;
        const int row = idxs[n * IDXW + s];
        const float4 v = *reinterpret_cast<const float4*>(all_emb + ((size_t)(n * L_ + row)) * D_ + d0 + dq);
        tile[dq + 0][s] = f2bf(v.x); tile[dq + 1][s] = f2bf(v.y);
        tile[dq + 2][s] = f2bf(v.z); tile[dq + 3][s] = f2bf(v.w);
    }
    __syncthreads();
#pragma unroll
    for (int it = 0; it < 8; ++it) {
        const int lin = threadIdx.x + 256 * it;      // 2048 ushort4 chunks
        const int d = lin >> 5, s4 = (lin & 31) * 4;
        ushort4 v = {tile[d][s4], tile[d][s4 + 1], tile[d][s4 + 2], tile[d][s4 + 3]};
        *reinterpret_cast<ushort4*>(sentT + ((size_t)(n * D_) + d0 + d) * S_ + s4) = v;
    }
}

// ---- transpose + bf16: entmapT[n][e][s] = ent_map[n][s][e] ----
__global__ __launch_bounds__(256) void entmapT_k(const float* __restrict__ ent_map,
                                                 unsigned short* __restrict__ entmapT) {
    const int n = blockIdx.x;
    __shared__ unsigned short tile[128][132];
#pragma unroll
    for (int it = 0; it < 16; ++it) {
        const int lin = threadIdx.x + 256 * it;      // 4096 float4 chunks
        const int s = lin >> 5, eq = (lin & 31) * 4;
        const float4 v = *reinterpret_cast<const float4*>(ent_map + ((size_t)(n * S_ + s)) * E_ + eq);
        tile[eq + 0][s] = f2bf(v.x); tile[eq + 1][s] = f2bf(v.y);
        tile[eq + 2][s] = f2bf(v.z); tile[eq + 3][s] = f2bf(v.w);
    }
    __syncthreads();
#pragma unroll
    for (int it = 0; it < 16; ++it) {
        const int lin = threadIdx.x + 256 * it;      // 4096 ushort4 chunks
        const int e = lin >> 5, s4 = (lin & 31) * 4;
        ushort4 v = {tile[e][s4], tile[e][s4 + 1], tile[e][s4 + 2], tile[e][s4 + 3]};
        *reinterpret_cast<ushort4*>(entmapT + ((size_t)(n * E_) + e) * S_ + s4) = v;
    }
}

// ---- W1 [4608 x 768] fp32 -> W1t [768 x 4608] bf16 ----
__global__ __launch_bounds__(256) void transpose_w1_k(const float* __restrict__ W1, short* __restrict__ W1t) {
    __shared__ float tile[64][65];
    const int k0 = blockIdx.x * 64, h0 = blockIdx.y * 64;
    const int tx = threadIdx.x & 63, ty = threadIdx.x >> 6;
#pragma unroll
    for (int i = 0; i < 16; ++i) {
        const int r = ty + i * 4;
        tile[r][tx] = W1[(size_t)(k0 + r) * H_ + h0 + tx];
    }
    __syncthreads();
#pragma unroll
    for (int i = 0; i < 16; ++i) {
        const int r = ty + i * 4;
        W1t[(size_t)(h0 + r) * W1R + k0 + tx] = (short)f2bf(tile[tx][r]);
    }
}

// ---- t2t[n,s,t] (bf16 out): head-sum in registers during load ----
// wave w (of 2) owns heads w*6..w*6+5; lane owns float4 column slice lane*4.
// LDS shrinks 49KB -> 6KB, barriers 13 -> 2.
__global__ __launch_bounds__(128) void t2t_k(const float* __restrict__ attn,
                                             const int* __restrict__ idxs,
                                             unsigned short* __restrict__ t2tbf) {
    const int n = blockIdx.x >> 7, s = blockIdx.x & 127;
    const int t = threadIdx.x;               // 0..127
    const int w = t >> 6, lane = t & 63;
    const int is = idxs[n * IDXW + s], it = idxs[n * IDXW + t];
    __shared__ float sum2[3][2][256];
    __shared__ float part[3][2];
#pragma unroll
    for (int l = 0; l < 3; ++l) {
        const float* base = attn + ((size_t)((l * N_ + n) * 12 + w * 6)) * (L_ * L_)
                          + (size_t)is * L_ + lane * 4;
        float4 acc = {0.f, 0.f, 0.f, 0.f};
#pragma unroll
        for (int h = 0; h < 6; ++h) {
            const float4 v = *reinterpret_cast<const float4*>(base + (size_t)h * (L_ * L_));
            acc.x += v.x; acc.y += v.y; acc.z += v.z; acc.w += v.w;
        }
        *reinterpret_cast<float4*>(&sum2[l][w][lane * 4]) = acc;
    }
    __syncthreads();
    float m[3];
#pragma unroll
    for (int l = 0; l < 3; ++l) {
        m[l] = (sum2[l][0][it] + sum2[l][1][it]) * (1.0f / 12.0f);
        float r = m[l];
#pragma unroll
        for (int off = 32; off; off >>= 1) r += __shfl_xor(r, off, 64);
        if (lane == 0) part[l][w] = r;
    }
    __syncthreads();
    float out = 0.f;
#pragma unroll
    for (int l = 0; l < 3; ++l)
        out += m[l] / (part[l][0] + part[l][1] + 1e-9f);
    t2tbf[((size_t)(n * S_ + s)) * S_ + t] = f2bf(out * (1.0f / 3.0f));
}

// ---- fused arg_emb + a2a softmax + u2u ----
__global__ __launch_bounds__(256) void arg_u2u_k(const float* __restrict__ all_emb,
                                                 const int* __restrict__ idxs,
                                                 const float* __restrict__ argw,
                                                 float* __restrict__ argE,
                                                 unsigned short* __restrict__ argEbf,
                                                 unsigned short* __restrict__ u2ubf) {
    const int n = blockIdx.x, tid = threadIdx.x;
    __shared__ float wsm[A_][A_];
    __shared__ float part[45][4];
    __shared__ float Psm[A_][A_];
    if (tid < A_ * A_) wsm[tid / A_][tid % A_] = argw[n * A_ * A_ + tid];
    __syncthreads();
    const int p0 = idxs[n * IDXW + S_] + 1;
    float pp[45] = {};
    float vals[3][A_];
#pragma unroll
    for (int c = 0; c < 3; ++c) {
        const int d = tid + 256 * c;
        float raw[A_];
#pragma unroll
        for (int k = 0; k < A_; ++k) raw[k] = all_emb[((size_t)(n * L_ + p0 + k)) * D_ + d];
#pragma unroll
        for (int a = 0; a < A_; ++a) {
            float acc = 0.f;
#pragma unroll
            for (int k = 0; k < A_; ++k) acc = fmaf(raw[k], wsm[k][a], acc);
            vals[c][a] = acc;
            argE[((size_t)(n * A_ + a)) * D_ + d] = acc;
            argEbf[((size_t)(n * A_ + a)) * D_ + d] = f2bf(acc);
        }
        int p = 0;
#pragma unroll
        for (int a = 0; a < A_; ++a)
#pragma unroll
            for (int b = a; b < A_; ++b) pp[p++] += vals[c][a] * vals[c][b];
    }
    const int lane = tid & 63, wv = tid >> 6;
#pragma unroll
    for (int p = 0; p < 45; ++p) {
        float v = pp[p];
        for (int off = 32; off; off >>= 1) v += __shfl_down(v, off, 64);
        if (lane == 0) part[p][wv] = v;
    }
    __syncthreads();
    if (tid < 45) part[tid][0] = part[tid][0] + part[tid][1] + part[tid][2] + part[tid][3];
    __syncthreads();
    if (tid < A_) {
        const int a = tid;
        float v[A_], mx = -1e30f;
#pragma unroll
        for (int b = 0; b < A_; ++b) {
            const int lo = a < b ? a : b, hi = a < b ? b : a;
            v[b] = part[lo * (19 - lo) / 2 + hi - lo][0];
            mx = fmaxf(mx, v[b]);
        }
        float s = 0.f;
#pragma unroll
        for (int b = 0; b < A_; ++b) { v[b] = expf(v[b] - mx); s += v[b]; }
        const float inv = 1.0f / s;
#pragma unroll
        for (int b = 0; b < A_; ++b) Psm[a][b] = v[b] * inv;
    }
    __syncthreads();
#pragma unroll
    for (int c = 0; c < 3; ++c) {
        const int d = tid + 256 * c;
#pragma unroll
        for (int a = 0; a < A_; ++a) {
            float acc = 0.f;
#pragma unroll
            for (int b = 0; b < A_; ++b) acc = fmaf(Psm[a][b], vals[c][b], acc);
            u2ubf[((size_t)(n * A_ + a)) * D_ + d] = f2bf(acc);
        }
    }
}

// ---- batched MFMA: C[n](128x768) = A[n](128x128, bf16, k-consecutive) @ B (from BT[n][768][128]) ----
// MODE 1: store bf16 transposed [768][128]; MODE 2: bf16 row-major
template <int MODE>
__global__ __launch_bounds__(256) void gemm128_k(const unsigned short* __restrict__ Ab,
                                                 const unsigned short* __restrict__ BTb,
                                                 float* __restrict__ Cf,
                                                 unsigned short* __restrict__ Cb) {
    __shared__ __align__(16) short As[128][40];
    __shared__ __align__(16) short Bs[64][40];
    const int n = blockIdx.y, c0 = blockIdx.x * 64;
    const unsigned short* A = Ab + (size_t)n * S_ * S_;
    const unsigned short* BT = BTb + (size_t)n * D_ * S_;
    const int tid = threadIdx.x;
    const int wave = tid >> 6, lane = tid & 63;
    const int row16 = lane & 15, quad = lane >> 4;
    f32x4v acc[2][4] = {};
    for (int k0 = 0; k0 < S_; k0 += 32) {
#pragma unroll
        for (int i = 0; i < 2; ++i) {
            const int idx = tid + 256 * i;
            const int r = idx >> 2, q = idx & 3;
            *reinterpret_cast<bshort8*>(&As[r][q * 8]) =
                *reinterpret_cast<const bshort8*>(A + (size_t)r * S_ + k0 + q * 8);
        }
        {
            const int col = tid >> 2, q = tid & 3;
            *reinterpret_cast<bshort8*>(&Bs[col][q * 8]) =
                *reinterpret_cast<const bshort8*>(BT + (size_t)(c0 + col) * S_ + k0 + q * 8);
        }
        __syncthreads();
        bshort8 a[2], b[4];
#pragma unroll
        for (int mi = 0; mi < 2; ++mi)
            a[mi] = *reinterpret_cast<const bshort8*>(&As[wave * 32 + mi * 16 + row16][quad * 8]);
#pragma unroll
        for (int ni = 0; ni < 4; ++ni)
            b[ni] = *reinterpret_cast<const bshort8*>(&Bs[ni * 16 + row16][quad * 8]);
#pragma unroll
        for (int mi = 0; mi < 2; ++mi)
#pragma unroll
            for (int ni = 0; ni < 4; ++ni)
                acc[mi][ni] = __builtin_amdgcn_mfma_f32_16x16x32_bf16(a[mi], b[ni], acc[mi][ni], 0, 0, 0);
        __syncthreads();
    }
#pragma unroll
    for (int mi = 0; mi < 2; ++mi) {
#pragma unroll
        for (int ni = 0; ni < 4; ++ni) {
            const int rbase = wave * 32 + mi * 16 + quad * 4;
            const int col = c0 + ni * 16 + row16;
            if (MODE == 1) {
                ushort4 v = {f2bf(acc[mi][ni][0]), f2bf(acc[mi][ni][1]),
                             f2bf(acc[mi][ni][2]), f2bf(acc[mi][ni][3])};
                *reinterpret_cast<ushort4*>(Cb + (size_t)n * D_ * S_ + (size_t)col * S_ + rbase) = v;
            } else {
#pragma unroll
                for (int t = 0; t < 4; ++t) {
                    const size_t o = ((size_t)n * S_ + rbase + t) * D_ + col;
                    Cb[o] = f2bf(acc[mi][ni][t]);
                }
            }
        }
    }
}

// ---- merged independent pair: z==0 -> h2hT = (t2t @ sent)^T (MODE1); z==1 -> ent = entmapT @ sent (fp32+bf16) ----
__global__ __launch_bounds__(256) void gemm_pair_k(const unsigned short* __restrict__ t2tbf,
                                                   const unsigned short* __restrict__ entmapT,
                                                   const unsigned short* __restrict__ sentT,
                                                   float* __restrict__ entf,
                                                   unsigned short* __restrict__ entbf,
                                                   unsigned short* __restrict__ h2hT) {
    __shared__ __align__(16) short As[128][40];
    __shared__ __align__(16) short Bs[64][40];
    const int n = blockIdx.y, c0 = blockIdx.x * 64, z = blockIdx.z;
    const unsigned short* A = (z == 0 ? t2tbf : entmapT) + (size_t)n * S_ * S_;
    const unsigned short* BT = sentT + (size_t)n * D_ * S_;
    const int tid = threadIdx.x;
    const int wave = tid >> 6, lane = tid & 63;
    const int row16 = lane & 15, quad = lane >> 4;
    f32x4v acc[2][4] = {};
    for (int k0 = 0; k0 < S_; k0 += 32) {
#pragma unroll
        for (int i = 0; i < 2; ++i) {
            const int idx = tid + 256 * i;
            const int r = idx >> 2, q = idx & 3;
            *reinterpret_cast<bshort8*>(&As[r][q * 8]) =
                *reinterpret_cast<const bshort8*>(A + (size_t)r * S_ + k0 + q * 8);
        }
        {
            const int col = tid >> 2, q = tid & 3;
            *reinterpret_cast<bshort8*>(&Bs[col][q * 8]) =
                *reinterpret_cast<const bshort8*>(BT + (size_t)(c0 + col) * S_ + k0 + q * 8);
        }
        __syncthreads();
        bshort8 a[2], b[4];
#pragma unroll
        for (int mi = 0; mi < 2; ++mi)
            a[mi] = *reinterpret_cast<const bshort8*>(&As[wave * 32 + mi * 16 + row16][quad * 8]);
#pragma unroll
        for (int ni = 0; ni < 4; ++ni)
            b[ni] = *reinterpret_cast<const bshort8*>(&Bs[ni * 16 + row16][quad * 8]);
#pragma unroll
        for (int mi = 0; mi < 2; ++mi)
#pragma unroll
            for (int ni = 0; ni < 4; ++ni)
                acc[mi][ni] = __builtin_amdgcn_mfma_f32_16x16x32_bf16(a[mi], b[ni], acc[mi][ni], 0, 0, 0);
        __syncthreads();
    }
#pragma unroll
    for (int mi = 0; mi < 2; ++mi) {
#pragma unroll
        for (int ni = 0; ni < 4; ++ni) {
            const int rbase = wave * 32 + mi * 16 + quad * 4;
            const int col = c0 + ni * 16 + row16;
            if (z == 0) {
                ushort4 v = {f2bf(acc[mi][ni][0]), f2bf(acc[mi][ni][1]),
                             f2bf(acc[mi][ni][2]), f2bf(acc[mi][ni][3])};
                *reinterpret_cast<ushort4*>(h2hT + (size_t)n * D_ * S_ + (size_t)col * S_ + rbase) = v;
            } else {
#pragma unroll
                for (int t = 0; t < 4; ++t) {
                    const size_t o = ((size_t)n * S_ + rbase + t) * D_ + col;
                    entf[o] = acc[mi][ni][t];
                    entbf[o] = f2bf(acc[mi][ni][t]);
                }
            }
        }
    }
}

// ---- fused w + tokA ----
__global__ __launch_bounds__(256) void w_tokA_k(const float* __restrict__ ent, const float* __restrict__ argE,
                                                float* __restrict__ wbuf, unsigned short* __restrict__ tokAbf) {
    const int n = blockIdx.x >> 7, e = blockIdx.x & 127;
    const int tid = threadIdx.x;
    const float* er = ent + ((size_t)(n * E_ + e)) * D_;
    const float* ar = argE + (size_t)n * A_ * D_;
    float acc[A_] = {};
    for (int d = tid; d < D_; d += 256) {
        const float ev = er[d];
#pragma unroll
        for (int a = 0; a < A_; ++a) acc[a] = fmaf(ev, ar[(size_t)a * D_ + d], acc[a]);
    }
    const int lane = tid & 63, wv = tid >> 6;
#pragma unroll
    for (int a = 0; a < A_; ++a)
        for (int off = 32; off; off >>= 1) acc[a] += __shfl_down(acc[a], off, 64);
    __shared__ float part[A_][4];
    __shared__ float wl[A_];
    if (lane == 0)
        for (int a = 0; a < A_; ++a) part[a][wv] = acc[a];
    __syncthreads();
    if (tid < A_) {
        const float s = part[tid][0] + part[tid][1] + part[tid][2] + part[tid][3];
        const float w = (s * INV_SQRT_D - 5.0f) * 0.5f;
        wl[tid] = w;
        wbuf[(size_t)(n * E_ + e) * A_ + tid] = w;
    }
    __syncthreads();
    for (int d = tid; d < D_; d += 256) {
        float s = 0.f;
#pragma unroll
        for (int a = 0; a < A_; ++a) s = fmaf(wl[a], ar[(size_t)a * D_ + d], s);
        tokAbf[((size_t)(n * E_ + e)) * D_ + d] = f2bf(s);
    }
}

// ---- argT[n,a,d] = sum_e w[n,e,a]*ent[n,e,d] (bf16 out) ----
__global__ __launch_bounds__(256) void argT_k(const float* __restrict__ wbuf, const float* __restrict__ ent,
                                              unsigned short* __restrict__ argTbf) {
    const int n = blockIdx.x / A_, a = blockIdx.x % A_;
    const int tid = threadIdx.x;
    __shared__ float wl[E_];
    if (tid < E_) wl[tid] = wbuf[(size_t)(n * E_ + tid) * A_ + a];
    __syncthreads();
    const float* eb = ent + (size_t)n * E_ * D_;
    for (int d = tid; d < D_; d += 256) {
        float acc = 0.f;
        for (int e = 0; e < E_; ++e) acc = fmaf(wl[e], eb[(size_t)e * D_ + d], acc);
        argTbf[((size_t)(n * A_ + a)) * D_ + d] = f2bf(acc);
    }
}

// ---- MLP layer 1, K-split by segment: 3x blocks, atomicAdd into zeroed Pe/Pa ----
__global__ __launch_bounds__(256) void mfma_mlp_k(const unsigned short* __restrict__ e0,
                                                  const unsigned short* __restrict__ e1,
                                                  const unsigned short* __restrict__ e2,
                                                  const unsigned short* __restrict__ a0,
                                                  const unsigned short* __restrict__ a1,
                                                  const unsigned short* __restrict__ a2,
                                                  const short* __restrict__ W1t,
                                                  float* __restrict__ Pe, float* __restrict__ Pa) {
    __shared__ __align__(16) short As[128][40];
    __shared__ __align__(16) short Bs[64][40];
    const int bx = blockIdx.x;          // 0..53
    const int seg = bx % 3;
    const int blk = bx / 3;             // 0..17 (16 Pe row-blocks + 2 Pa row-blocks)
    const bool isPa = blk >= 16;
    const unsigned short* Aseg;
    int woff;
    if (isPa) {
        Aseg = seg == 0 ? a0 : (seg == 1 ? a1 : a2);
        woff = seg == 0 ? 1 * D_ : (seg == 1 ? 4 * D_ : 5 * D_);
    } else {
        Aseg = seg == 0 ? e0 : (seg == 1 ? e1 : e2);
        woff = seg == 0 ? 0 : (seg == 1 ? 2 * D_ : 3 * D_);
    }
    const int M = isPa ? N_ * A_ : N_ * E_;
    const int r0 = (isPa ? blk - 16 : blk) * 128;
    float* C = isPa ? Pa : Pe;
    const int c0 = blockIdx.y * 64;
    const int tid = threadIdx.x;
    const int wave = tid >> 6, lane = tid & 63;
    const int row16 = lane & 15, quad = lane >> 4;
    f32x4v acc[2][4] = {};
    for (int kk = 0; kk < D_; kk += 32) {
#pragma unroll
        for (int i = 0; i < 2; ++i) {
            const int idx = tid + 256 * i;
            const int r = idx >> 2, q = idx & 3;
            bshort8 av = {};
            if (r0 + r < M) av = *reinterpret_cast<const bshort8*>(Aseg + (size_t)(r0 + r) * D_ + kk + q * 8);
            *reinterpret_cast<bshort8*>(&As[r][q * 8]) = av;
        }
        {
            const int col = tid >> 2, q = tid & 3;
            *reinterpret_cast<bshort8*>(&Bs[col][q * 8]) =
                *reinterpret_cast<const bshort8*>(W1t + (size_t)(c0 + col) * W1R + woff + kk + q * 8);
        }
        __syncthreads();
        bshort8 a[2], b[4];
#pragma unroll
        for (int mi = 0; mi < 2; ++mi)
            a[mi] = *reinterpret_cast<const bshort8*>(&As[wave * 32 + mi * 16 + row16][quad * 8]);
#pragma unroll
        for (int ni = 0; ni < 4; ++ni)
            b[ni] = *reinterpret_cast<const bshort8*>(&Bs[ni * 16 + row16][quad * 8]);
#pragma unroll
        for (int mi = 0; mi < 2; ++mi)
#pragma unroll
            for (int ni = 0; ni < 4; ++ni)
                acc[mi][ni] = __builtin_amdgcn_mfma_f32_16x16x32_bf16(a[mi], b[ni], acc[mi][ni], 0, 0, 0);
        __syncthreads();
    }
#pragma unroll
    for (int mi = 0; mi < 2; ++mi) {
#pragma unroll
        for (int ni = 0; ni < 4; ++ni) {
            const int rbase = r0 + wave * 32 + mi * 16 + quad * 4;
            const int col = c0 + ni * 16 + row16;
#pragma unroll
            for (int t = 0; t < 4; ++t)
                if (rbase + t < M) atomicAdd(&C[(size_t)(rbase + t) * H_ + col], acc[mi][ni][t]);
        }
    }
}

// ---- epilogue: gelu(Pe+Pa+b1)@W2 + b2, scatter ----
__global__ __launch_bounds__(256) void score_k(const float* __restrict__ Pe, const float* __restrict__ Pa,
                                               const float* __restrict__ b1, const float* __restrict__ W2,
                                               const float* __restrict__ b2, const int* __restrict__ arg_map,
                                               float* __restrict__ out) {
    const int n = blockIdx.x >> 7, e = blockIdx.x & 127;
    const int tid = threadIdx.x;
    __shared__ float paS[A_ * H_];
    __shared__ float part[A_][4];
    float* orow = out + ((size_t)(n * E_ + e)) * RO_;
    if (tid < RO_) orow[tid] = -1000000.0f;
    for (int i = tid; i < A_ * H_; i += 256) paS[i] = Pa[(size_t)n * A_ * H_ + i];
    __syncthreads();
    const float* per = Pe + ((size_t)(n * E_ + e)) * H_;
    float acc[A_] = {};
    for (int h = tid; h < H_; h += 256) {
        const float pe = per[h] + b1[h];
        const float w2 = W2[h];
#pragma unroll
        for (int a = 0; a < A_; ++a) {
            const float x = pe + paS[a * H_ + h];
            const float g = x * 0.5f * (1.0f + erff(x * 0.70710678118654752f));
            acc[a] = fmaf(g, w2, acc[a]);
        }
    }
    const int lane = tid & 63, wv = tid >> 6;
#pragma unroll
    for (int a = 0; a < A_; ++a)
        for (int off = 32; off; off >>= 1) acc[a] += __shfl_down(acc[a], off, 64);
    if (lane == 0)
        for (int a = 0; a < A_; ++a) part[a][wv] = acc[a];
    __syncthreads();
    if (tid < A_) {
        const float s = part[tid][0] + part[tid][1] + part[tid][2] + part[tid][3] + b2[0];
        orow[arg_map[n * A_ + tid]] = s;
    }
}

extern "C" void kernel_launch(void* const* d_in, const int* in_sizes, int n_in,
                              void* d_out, int out_size, void* d_ws, size_t ws_size,
                              hipStream_t stream) {
    const float* all_emb = (const float*)d_in[0];
    const float* attn    = (const float*)d_in[1];
    const float* ent_map = (const float*)d_in[2];
    const float* argw    = (const float*)d_in[3];
    // d_in[4] is_triggers unused (reference dead code)
    const float* W1 = (const float*)d_in[5];
    const float* b1 = (const float*)d_in[6];
    const float* W2 = (const float*)d_in[7];
    const float* b2 = (const float*)d_in[8];
    const int* idxs    = (const int*)d_in[9];
    const int* arg_map = (const int*)d_in[10];
    float* out = (float*)d_out;

    float* ws = (float*)d_ws;
    // fp32 buffers (float offsets)
    float* entf = ws + 0;               // N*E*D = 1,572,864
    float* Pe   = ws + 1572864;         // N*E*H = 1,572,864
    float* argE = ws + 3145728;         // N*A*D = 110,592
    float* wbuf = ws + 3256320;         // N*E*A = 18,432
    float* Pa   = ws + 3274752;         // N*A*H = 110,592
    // bf16 buffers (sizes in float-slots = shorts/2)
    short*          W1t     = (short*)(ws + 3385344);          // 768*4608
    unsigned short* sentT   = (unsigned short*)(ws + 5154816); // N*D*S
    unsigned short* entmapT = (unsigned short*)(ws + 5941248); // N*E*S
    unsigned short* t2tbf   = (unsigned short*)(ws + 6072320); // N*S*S
    unsigned short* argEbf  = (unsigned short*)(ws + 6127616); // N*A*D
    unsigned short* u2ubf   = (unsigned short*)(ws + 6182912); // N*A*D
    unsigned short* entbf   = (unsigned short*)(ws + 6238208); // N*E*D
    unsigned short* h2hT    = (unsigned short*)(ws + 7024640); // N*D*S
    unsigned short* Ah2hbf  = (unsigned short*)(ws + 7811072); // N*E*D
    unsigned short* tokAbf  = (unsigned short*)(ws + 8597504); // N*E*D
    unsigned short* argTbf  = (unsigned short*)(ws + 9383936); // N*A*D
    // total ≈ 9,439,232 floats = 37.8 MB

    // stage 0: zero accumulators for mfma_mlp atomics (off critical path)
    zero2_k<<<(N_ * E_ * H_) / 4 / 256, 256, 0, stream>>>(Pe, Pa);

    // stage 1: layout transforms + gathers (independent)
    gatherT_k<<<dim3(N_, D_ / 64), 256, 0, stream>>>(all_emb, idxs, sentT);
    entmapT_k<<<N_, 256, 0, stream>>>(ent_map, entmapT);
    transpose_w1_k<<<dim3(W1R / 64, H_ / 64), 256, 0, stream>>>(W1, W1t);
    t2t_k<<<N_ * S_, 128, 0, stream>>>(attn, idxs, t2tbf);
    arg_u2u_k<<<N_, 256, 0, stream>>>(all_emb, idxs, argw, argE, argEbf, u2ubf);

    // stage 2: batched MFMA GEMMs
    // merged: z=0 -> h2hT = (t2t @ sent)^T ; z=1 -> ent = entmapT @ sent
    gemm_pair_k<<<dim3(D_ / 64, N_, 2), 256, 0, stream>>>(t2tbf, entmapT, sentT, entf, entbf, h2hT);
    // Ah2h = ent_map^T @ h2h (bf16) — depends on h2hT
    gemm128_k<2><<<dim3(D_ / 64, N_), 256, 0, stream>>>(entmapT, h2hT, nullptr, Ah2hbf);

    // stage 3: interactions
    w_tokA_k<<<N_ * E_, 256, 0, stream>>>(entf, argE, wbuf, tokAbf);
    argT_k<<<N_ * A_, 256, 0, stream>>>(wbuf, entf, argTbf);

    // stage 4: MLP layer 1, K-split by segment (648 blocks), atomic accumulate
    // W1 row blocks: [ent 0 | argE 768 | tokA 1536 | Ah2h 2304 | argT 3072 | u2u 3840]
    mfma_mlp_k<<<dim3(54, H_ / 64), 256, 0, stream>>>(entbf, tokAbf, Ah2hbf, argEbf, argTbf, u2ubf, W1t, Pe, Pa);

    // stage 5: gelu + W2 + scatter
    score_k<<<N_ * E_, 256, 0, stream>>>(Pe, Pa, b1, W2, b2, arg_map, out);

    (void)in_sizes; (void)n_in; (void)out_size; (void)ws_size;
}

// Round 2
// 318.172 us; speedup vs baseline: 1.1022x; 1.1022x over previous
//
#include <hip/hip_runtime.h>
#include <math.h>

namespace {
constexpr int N_ = 16, L_ = 256, S_ = 128, E_ = 128, A_ = 9, D_ = 768, H_ = 768, RO_ = 24;
constexpr int IDXW = 130;       // S+2
constexpr int W1R = 6 * D_;     // 4608
constexpr float INV_SQRT_D = 0.03608439182435161f; // 1/sqrt(768)
constexpr int PESZ = 2048 * 768;   // one Pe partial
constexpr int PASZ = 144 * 768;    // one Pa partial
// stage1 mega-kernel block ranges
constexpr int GB_GATHER = 0;       // 192 blocks (16 n x 12 d-tiles)
constexpr int GB_ENTMAP = 192;     // 16
constexpr int GB_W1T    = 208;     // 864 (72 k-tiles x 12 h-tiles)
constexpr int GB_T2T    = 1072;    // 1024 (16 n x 64 s-pairs)
constexpr int GB_ARGU   = 2096;    // 16
constexpr int GB_TOTAL  = 2112;
} // namespace

using bshort8 = __attribute__((ext_vector_type(8))) short;
using f32x4v = __attribute__((ext_vector_type(4))) float;

__device__ __forceinline__ unsigned short f2bf(float f) {
    unsigned u = __builtin_bit_cast(unsigned, f);
    return (unsigned short)((u + 0x7fffu + ((u >> 16) & 1u)) >> 16);
}

// ======== stage 1 mega-kernel: all independent transforms in one launch ========
__global__ __launch_bounds__(256) void stage1_k(const float* __restrict__ all_emb,
                                                const int* __restrict__ idxs,
                                                const float* __restrict__ ent_map,
                                                const float* __restrict__ W1,
                                                const float* __restrict__ argw,
                                                const float* __restrict__ attn,
                                                unsigned short* __restrict__ sentT,
                                                unsigned short* __restrict__ entmapT,
                                                short* __restrict__ W1t,
                                                unsigned short* __restrict__ t2tbf,
                                                float* __restrict__ argE,
                                                unsigned short* __restrict__ argEbf,
                                                unsigned short* __restrict__ u2ubf) {
    __shared__ __align__(16) unsigned char smem[33792];
    const int b = blockIdx.x, tid = threadIdx.x;

    if (b < GB_ENTMAP) {
        // ---- gatherT: sentT[n][d][s] = bf16(all_emb[n][idx[s]][d]) ----
        const int n = b / 12, d0 = (b % 12) * 64;
        auto tile = (unsigned short (*)[132])smem;   // [64][132]
#pragma unroll
        for (int it = 0; it < 8; ++it) {
            const int lin = tid + 256 * it;
            const int s = lin >> 4, dq = (lin & 15) * 4;
            const int row = idxs[n * IDXW + s];
            const float4 v = *reinterpret_cast<const float4*>(all_emb + ((size_t)(n * L_ + row)) * D_ + d0 + dq);
            tile[dq + 0][s] = f2bf(v.x); tile[dq + 1][s] = f2bf(v.y);
            tile[dq + 2][s] = f2bf(v.z); tile[dq + 3][s] = f2bf(v.w);
        }
        __syncthreads();
#pragma unroll
        for (int it = 0; it < 8; ++it) {
            const int lin = tid + 256 * it;
            const int d = lin >> 5, s4 = (lin & 31) * 4;
            ushort4 v = {tile[d][s4], tile[d][s4 + 1], tile[d][s4 + 2], tile[d][s4 + 3]};
            *reinterpret_cast<ushort4*>(sentT + ((size_t)(n * D_) + d0 + d) * S_ + s4) = v;
        }
    } else if (b < GB_W1T) {
        // ---- entmapT[n][e][s] = bf16(ent_map[n][s][e]) ----
        const int n = b - GB_ENTMAP;
        auto tile = (unsigned short (*)[132])smem;   // [128][132] = 33792B
#pragma unroll
        for (int it = 0; it < 16; ++it) {
            const int lin = tid + 256 * it;
            const int s = lin >> 5, eq = (lin & 31) * 4;
            const float4 v = *reinterpret_cast<const float4*>(ent_map + ((size_t)(n * S_ + s)) * E_ + eq);
            tile[eq + 0][s] = f2bf(v.x); tile[eq + 1][s] = f2bf(v.y);
            tile[eq + 2][s] = f2bf(v.z); tile[eq + 3][s] = f2bf(v.w);
        }
        __syncthreads();
#pragma unroll
        for (int it = 0; it < 16; ++it) {
            const int lin = tid + 256 * it;
            const int e = lin >> 5, s4 = (lin & 31) * 4;
            ushort4 v = {tile[e][s4], tile[e][s4 + 1], tile[e][s4 + 2], tile[e][s4 + 3]};
            *reinterpret_cast<ushort4*>(entmapT + ((size_t)(n * E_) + e) * S_ + s4) = v;
        }
    } else if (b < GB_T2T) {
        // ---- W1t[h][k] = bf16(W1[k][h]) ----
        const int b2 = b - GB_W1T;
        const int k0 = (b2 % 72) * 64, h0 = (b2 / 72) * 64;
        auto tile = (float (*)[65])smem;             // [64][65] = 16640B
        const int tx = tid & 63, ty = tid >> 6;
#pragma unroll
        for (int i = 0; i < 16; ++i) {
            const int r = ty + i * 4;
            tile[r][tx] = W1[(size_t)(k0 + r) * H_ + h0 + tx];
        }
        __syncthreads();
#pragma unroll
        for (int i = 0; i < 16; ++i) {
            const int r = ty + i * 4;
            W1t[(size_t)(h0 + r) * W1R + k0 + tx] = (short)f2bf(tile[tx][r]);
        }
    } else if (b < GB_ARGU) {
        // ---- t2t: two s-rows per block (256 thr = 2 halves x 2 waves) ----
        const int idx = b - GB_T2T;
        const int n = idx >> 6;
        const int half = tid >> 7, t128 = tid & 127;
        const int s = ((idx & 63) << 1) | half;
        const int w = t128 >> 6, lane = tid & 63;
        float* sum2 = (float*)smem;                  // [2][3][2][256] = 12288B
        float* part = (float*)(smem + 12288);        // [2][3][2]
        const int is = idxs[n * IDXW + s], it = idxs[n * IDXW + t128];
#pragma unroll
        for (int l = 0; l < 3; ++l) {
            const float* base = attn + ((size_t)((l * N_ + n) * 12 + w * 6)) * (L_ * L_)
                              + (size_t)is * L_ + lane * 4;
            float4 acc = {0.f, 0.f, 0.f, 0.f};
#pragma unroll
            for (int h = 0; h < 6; ++h) {
                const float4 v = *reinterpret_cast<const float4*>(base + (size_t)h * (L_ * L_));
                acc.x += v.x; acc.y += v.y; acc.z += v.z; acc.w += v.w;
            }
            *reinterpret_cast<float4*>(&sum2[(((half * 3 + l) * 2 + w) << 8) + lane * 4]) = acc;
        }
        __syncthreads();
        float m[3];
#pragma unroll
        for (int l = 0; l < 3; ++l) {
            m[l] = (sum2[(((half * 3 + l) * 2 + 0) << 8) + it] +
                    sum2[(((half * 3 + l) * 2 + 1) << 8) + it]) * (1.0f / 12.0f);
            float r = m[l];
#pragma unroll
            for (int off = 32; off; off >>= 1) r += __shfl_xor(r, off, 64);
            if (lane == 0) part[(half * 3 + l) * 2 + w] = r;
        }
        __syncthreads();
        float out = 0.f;
#pragma unroll
        for (int l = 0; l < 3; ++l)
            out += m[l] / (part[(half * 3 + l) * 2 + 0] + part[(half * 3 + l) * 2 + 1] + 1e-9f);
        t2tbf[((size_t)(n * S_ + s)) * S_ + t128] = f2bf(out * (1.0f / 3.0f));
    } else {
        // ---- arg_u2u: arg_emb + a2a softmax + u2u ----
        const int n = b - GB_ARGU;
        auto wsm = (float (*)[A_])smem;              // 324B
        auto part45 = (float (*)[4])(smem + 512);    // 720B
        auto Psm = (float (*)[A_])(smem + 1536);     // 324B
        if (tid < A_ * A_) wsm[tid / A_][tid % A_] = argw[n * A_ * A_ + tid];
        __syncthreads();
        const int p0 = idxs[n * IDXW + S_] + 1;
        float pp[45] = {};
        float vals[3][A_];
#pragma unroll
        for (int c = 0; c < 3; ++c) {
            const int d = tid + 256 * c;
            float raw[A_];
#pragma unroll
            for (int k = 0; k < A_; ++k) raw[k] = all_emb[((size_t)(n * L_ + p0 + k)) * D_ + d];
#pragma unroll
            for (int a = 0; a < A_; ++a) {
                float acc = 0.f;
#pragma unroll
                for (int k = 0; k < A_; ++k) acc = fmaf(raw[k], wsm[k][a], acc);
                vals[c][a] = acc;
                argE[((size_t)(n * A_ + a)) * D_ + d] = acc;
                argEbf[((size_t)(n * A_ + a)) * D_ + d] = f2bf(acc);
            }
            int p = 0;
#pragma unroll
            for (int a = 0; a < A_; ++a)
#pragma unroll
                for (int bb = a; bb < A_; ++bb) pp[p++] += vals[c][a] * vals[c][bb];
        }
        const int lane = tid & 63, wv = tid >> 6;
#pragma unroll
        for (int p = 0; p < 45; ++p) {
            float v = pp[p];
            for (int off = 32; off; off >>= 1) v += __shfl_down(v, off, 64);
            if (lane == 0) part45[p][wv] = v;
        }
        __syncthreads();
        if (tid < 45) part45[tid][0] = part45[tid][0] + part45[tid][1] + part45[tid][2] + part45[tid][3];
        __syncthreads();
        if (tid < A_) {
            const int a = tid;
            float v[A_], mx = -1e30f;
#pragma unroll
            for (int bb = 0; bb < A_; ++bb) {
                const int lo = a < bb ? a : bb, hi = a < bb ? bb : a;
                v[bb] = part45[lo * (19 - lo) / 2 + hi - lo][0];
                mx = fmaxf(mx, v[bb]);
            }
            float sm = 0.f;
#pragma unroll
            for (int bb = 0; bb < A_; ++bb) { v[bb] = expf(v[bb] - mx); sm += v[bb]; }
            const float inv = 1.0f / sm;
#pragma unroll
            for (int bb = 0; bb < A_; ++bb) Psm[a][bb] = v[bb] * inv;
        }
        __syncthreads();
#pragma unroll
        for (int c = 0; c < 3; ++c) {
            const int d = tid + 256 * c;
#pragma unroll
            for (int a = 0; a < A_; ++a) {
                float acc = 0.f;
#pragma unroll
                for (int bb = 0; bb < A_; ++bb) acc = fmaf(Psm[a][bb], vals[c][bb], acc);
                u2ubf[((size_t)(n * A_ + a)) * D_ + d] = f2bf(acc);
            }
        }
    }
}

// ======== stage 2a: merged independent pair (z=0: h2hT, z=1: ent) ========
__global__ __launch_bounds__(256) void gemm_pair_k(const unsigned short* __restrict__ t2tbf,
                                                   const unsigned short* __restrict__ entmapT,
                                                   const unsigned short* __restrict__ sentT,
                                                   float* __restrict__ entf,
                                                   unsigned short* __restrict__ entbf,
                                                   unsigned short* __restrict__ h2hT) {
    __shared__ __align__(16) short As[128][40];
    __shared__ __align__(16) short Bs[64][40];
    const int n = blockIdx.y, c0 = blockIdx.x * 64, z = blockIdx.z;
    const unsigned short* A = (z == 0 ? t2tbf : entmapT) + (size_t)n * S_ * S_;
    const unsigned short* BT = sentT + (size_t)n * D_ * S_;
    const int tid = threadIdx.x;
    const int wave = tid >> 6, lane = tid & 63;
    const int row16 = lane & 15, quad = lane >> 4;
    f32x4v acc[2][4] = {};
    for (int k0 = 0; k0 < S_; k0 += 32) {
#pragma unroll
        for (int i = 0; i < 2; ++i) {
            const int idx = tid + 256 * i;
            const int r = idx >> 2, q = idx & 3;
            *reinterpret_cast<bshort8*>(&As[r][q * 8]) =
                *reinterpret_cast<const bshort8*>(A + (size_t)r * S_ + k0 + q * 8);
        }
        {
            const int col = tid >> 2, q = tid & 3;
            *reinterpret_cast<bshort8*>(&Bs[col][q * 8]) =
                *reinterpret_cast<const bshort8*>(BT + (size_t)(c0 + col) * S_ + k0 + q * 8);
        }
        __syncthreads();
        bshort8 a[2], b[4];
#pragma unroll
        for (int mi = 0; mi < 2; ++mi)
            a[mi] = *reinterpret_cast<const bshort8*>(&As[wave * 32 + mi * 16 + row16][quad * 8]);
#pragma unroll
        for (int ni = 0; ni < 4; ++ni)
            b[ni] = *reinterpret_cast<const bshort8*>(&Bs[ni * 16 + row16][quad * 8]);
#pragma unroll
        for (int mi = 0; mi < 2; ++mi)
#pragma unroll
            for (int ni = 0; ni < 4; ++ni)
                acc[mi][ni] = __builtin_amdgcn_mfma_f32_16x16x32_bf16(a[mi], b[ni], acc[mi][ni], 0, 0, 0);
        __syncthreads();
    }
#pragma unroll
    for (int mi = 0; mi < 2; ++mi) {
#pragma unroll
        for (int ni = 0; ni < 4; ++ni) {
            const int rbase = wave * 32 + mi * 16 + quad * 4;
            const int col = c0 + ni * 16 + row16;
            if (z == 0) {
                ushort4 v = {f2bf(acc[mi][ni][0]), f2bf(acc[mi][ni][1]),
                             f2bf(acc[mi][ni][2]), f2bf(acc[mi][ni][3])};
                *reinterpret_cast<ushort4*>(h2hT + (size_t)n * D_ * S_ + (size_t)col * S_ + rbase) = v;
            } else {
#pragma unroll
                for (int t = 0; t < 4; ++t) {
                    const size_t o = ((size_t)n * S_ + rbase + t) * D_ + col;
                    entf[o] = acc[mi][ni][t];
                    entbf[o] = f2bf(acc[mi][ni][t]);
                }
            }
        }
    }
}

// ======== stage 2b: Ah2h GEMM (192 blocks) + t2a/w MFMA (16 blocks) ========
__global__ __launch_bounds__(256) void gemm2_k(const unsigned short* __restrict__ entmapT,
                                               const unsigned short* __restrict__ h2hT,
                                               const unsigned short* __restrict__ entbf,
                                               const unsigned short* __restrict__ argEbf,
                                               unsigned short* __restrict__ Ah2hbf,
                                               float* __restrict__ wbuf) {
    const int bx = blockIdx.x, tid = threadIdx.x;
    const int wave = tid >> 6, lane = tid & 63;
    const int row16 = lane & 15, quad = lane >> 4;
    if (bx < 192) {
        // Ah2h[n] = entmapT[n] @ h2h ; BT = h2hT
        __shared__ __align__(16) short As[128][40];
        __shared__ __align__(16) short Bs[64][40];
        const int n = bx / 12, c0 = (bx % 12) * 64;
        const unsigned short* A = entmapT + (size_t)n * S_ * S_;
        const unsigned short* BT = h2hT + (size_t)n * D_ * S_;
        f32x4v acc[2][4] = {};
        for (int k0 = 0; k0 < S_; k0 += 32) {
#pragma unroll
            for (int i = 0; i < 2; ++i) {
                const int idx = tid + 256 * i;
                const int r = idx >> 2, q = idx & 3;
                *reinterpret_cast<bshort8*>(&As[r][q * 8]) =
                    *reinterpret_cast<const bshort8*>(A + (size_t)r * S_ + k0 + q * 8);
            }
            {
                const int col = tid >> 2, q = tid & 3;
                *reinterpret_cast<bshort8*>(&Bs[col][q * 8]) =
                    *reinterpret_cast<const bshort8*>(BT + (size_t)(c0 + col) * S_ + k0 + q * 8);
            }
            __syncthreads();
            bshort8 a[2], b[4];
#pragma unroll
            for (int mi = 0; mi < 2; ++mi)
                a[mi] = *reinterpret_cast<const bshort8*>(&As[wave * 32 + mi * 16 + row16][quad * 8]);
#pragma unroll
            for (int ni = 0; ni < 4; ++ni)
                b[ni] = *reinterpret_cast<const bshort8*>(&Bs[ni * 16 + row16][quad * 8]);
#pragma unroll
            for (int mi = 0; mi < 2; ++mi)
#pragma unroll
                for (int ni = 0; ni < 4; ++ni)
                    acc[mi][ni] = __builtin_amdgcn_mfma_f32_16x16x32_bf16(a[mi], b[ni], acc[mi][ni], 0, 0, 0);
            __syncthreads();
        }
#pragma unroll
        for (int mi = 0; mi < 2; ++mi)
#pragma unroll
            for (int ni = 0; ni < 4; ++ni) {
                const int rbase = wave * 32 + mi * 16 + quad * 4;
                const int col = c0 + ni * 16 + row16;
#pragma unroll
                for (int t = 0; t < 4; ++t)
                    Ah2hbf[((size_t)n * S_ + rbase + t) * D_ + col] = f2bf(acc[mi][ni][t]);
            }
    } else {
        // t2a via MFMA: C[128][16] = entbf[n](128x768) @ argEbf[n](9x768 padded)^T
        // then w = (C/sqrt(D) - 5)/2 -> wbuf[n][e][a]
        const int n = bx - 192;
        const unsigned short* Aent = entbf + (size_t)n * E_ * D_;
        const unsigned short* Barg = argEbf + (size_t)n * A_ * D_;
        f32x4v acc[2] = {};
        for (int k0 = 0; k0 < D_; k0 += 32) {
            bshort8 a[2], b;
#pragma unroll
            for (int mi = 0; mi < 2; ++mi)
                a[mi] = *reinterpret_cast<const bshort8*>(Aent + (size_t)(wave * 32 + mi * 16 + row16) * D_ + k0 + quad * 8);
            // rows 9..15 read past argE[n] into adjacent workspace (allocated); cols 9..15 discarded
            b = *reinterpret_cast<const bshort8*>(Barg + (size_t)row16 * D_ + k0 + quad * 8);
#pragma unroll
            for (int mi = 0; mi < 2; ++mi)
                acc[mi] = __builtin_amdgcn_mfma_f32_16x16x32_bf16(a[mi], b, acc[mi], 0, 0, 0);
        }
        if (row16 < A_) {
#pragma unroll
            for (int mi = 0; mi < 2; ++mi)
#pragma unroll
                for (int t = 0; t < 4; ++t) {
                    const int e = wave * 32 + mi * 16 + quad * 4 + t;
                    const float w = (acc[mi][t] * INV_SQRT_D - 5.0f) * 0.5f;
                    wbuf[((size_t)(n * E_ + e)) * A_ + row16] = w;
                }
        }
    }
}

// ======== stage 3: tokA (2048 blocks) + argT (144 blocks), both read wbuf ========
__global__ __launch_bounds__(256) void post_k(const float* __restrict__ wbuf,
                                              const float* __restrict__ argE,
                                              const float* __restrict__ entf,
                                              unsigned short* __restrict__ tokAbf,
                                              unsigned short* __restrict__ argTbf) {
    const int b = blockIdx.x, tid = threadIdx.x;
    if (b < N_ * E_) {
        // tokA[n,e,:] = sum_a w[n,e,a]*argE[n,a,:]
        const int n = b >> 7, e = b & 127;
        __shared__ float wl[A_];
        if (tid < A_) wl[tid] = wbuf[(size_t)(n * E_ + e) * A_ + tid];
        __syncthreads();
        const float* ar = argE + (size_t)n * A_ * D_;
#pragma unroll
        for (int c = 0; c < 3; ++c) {
            const int d = tid + 256 * c;
            float s = 0.f;
#pragma unroll
            for (int a = 0; a < A_; ++a) s = fmaf(wl[a], ar[(size_t)a * D_ + d], s);
            tokAbf[((size_t)(n * E_ + e)) * D_ + d] = f2bf(s);
        }
    } else {
        // argT[n,a,:] = sum_e w[n,e,a]*ent[n,e,:]
        const int idx = b - N_ * E_;
        const int n = idx / A_, a = idx % A_;
        __shared__ float wl[E_];
        if (tid < E_) wl[tid] = wbuf[(size_t)(n * E_ + tid) * A_ + a];
        __syncthreads();
        const float* eb = entf + (size_t)n * E_ * D_;
#pragma unroll
        for (int c = 0; c < 3; ++c) {
            const int d = tid + 256 * c;
            float acc = 0.f;
            for (int e = 0; e < E_; ++e) acc = fmaf(wl[e], eb[(size_t)e * D_ + d], acc);
            argTbf[((size_t)(n * A_ + a)) * D_ + d] = f2bf(acc);
        }
    }
}

// ======== stage 4: MLP layer 1, K-split into 3 disjoint partial buffers (no atomics) ========
__global__ __launch_bounds__(256) void mfma_mlp_k(const unsigned short* __restrict__ e0,
                                                  const unsigned short* __restrict__ e1,
                                                  const unsigned short* __restrict__ e2,
                                                  const unsigned short* __restrict__ a0,
                                                  const unsigned short* __restrict__ a1,
                                                  const unsigned short* __restrict__ a2,
                                                  const short* __restrict__ W1t,
                                                  float* __restrict__ Pe3, float* __restrict__ Pa3) {
    __shared__ __align__(16) short As[128][40];
    __shared__ __align__(16) short Bs[64][40];
    const int bx = blockIdx.x;          // 0..53
    const int seg = bx % 3;
    const int blk = bx / 3;             // 0..17 (16 Pe row-blocks + 2 Pa row-blocks)
    const bool isPa = blk >= 16;
    const unsigned short* Aseg;
    int woff;
    if (isPa) {
        Aseg = seg == 0 ? a0 : (seg == 1 ? a1 : a2);
        woff = seg == 0 ? 1 * D_ : (seg == 1 ? 4 * D_ : 5 * D_);
    } else {
        Aseg = seg == 0 ? e0 : (seg == 1 ? e1 : e2);
        woff = seg == 0 ? 0 : (seg == 1 ? 2 * D_ : 3 * D_);
    }
    const int M = isPa ? N_ * A_ : N_ * E_;
    const int r0 = (isPa ? blk - 16 : blk) * 128;
    float* C = isPa ? (Pa3 + (size_t)seg * PASZ) : (Pe3 + (size_t)seg * PESZ);
    const int c0 = blockIdx.y * 64;
    const int tid = threadIdx.x;
    const int wave = tid >> 6, lane = tid & 63;
    const int row16 = lane & 15, quad = lane >> 4;
    f32x4v acc[2][4] = {};
    for (int kk = 0; kk < D_; kk += 32) {
#pragma unroll
        for (int i = 0; i < 2; ++i) {
            const int idx = tid + 256 * i;
            const int r = idx >> 2, q = idx & 3;
            bshort8 av = {};
            if (r0 + r < M) av = *reinterpret_cast<const bshort8*>(Aseg + (size_t)(r0 + r) * D_ + kk + q * 8);
            *reinterpret_cast<bshort8*>(&As[r][q * 8]) = av;
        }
        {
            const int col = tid >> 2, q = tid & 3;
            *reinterpret_cast<bshort8*>(&Bs[col][q * 8]) =
                *reinterpret_cast<const bshort8*>(W1t + (size_t)(c0 + col) * W1R + woff + kk + q * 8);
        }
        __syncthreads();
        bshort8 a[2], b[4];
#pragma unroll
        for (int mi = 0; mi < 2; ++mi)
            a[mi] = *reinterpret_cast<const bshort8*>(&As[wave * 32 + mi * 16 + row16][quad * 8]);
#pragma unroll
        for (int ni = 0; ni < 4; ++ni)
            b[ni] = *reinterpret_cast<const bshort8*>(&Bs[ni * 16 + row16][quad * 8]);
#pragma unroll
        for (int mi = 0; mi < 2; ++mi)
#pragma unroll
            for (int ni = 0; ni < 4; ++ni)
                acc[mi][ni] = __builtin_amdgcn_mfma_f32_16x16x32_bf16(a[mi], b[ni], acc[mi][ni], 0, 0, 0);
        __syncthreads();
    }
#pragma unroll
    for (int mi = 0; mi < 2; ++mi) {
#pragma unroll
        for (int ni = 0; ni < 4; ++ni) {
            const int rbase = r0 + wave * 32 + mi * 16 + quad * 4;
            const int col = c0 + ni * 16 + row16;
#pragma unroll
            for (int t = 0; t < 4; ++t)
                if (rbase + t < M) C[(size_t)(rbase + t) * H_ + col] = acc[mi][ni][t];
        }
    }
}

// ======== stage 5: gelu(Pe0+Pe1+Pe2+Pa+b1)@W2 + b2, scatter ========
__global__ __launch_bounds__(256) void score_k(const float* __restrict__ Pe3, const float* __restrict__ Pa3,
                                               const float* __restrict__ b1, const float* __restrict__ W2,
                                               const float* __restrict__ b2, const int* __restrict__ arg_map,
                                               float* __restrict__ out) {
    const int n = blockIdx.x >> 7, e = blockIdx.x & 127;
    const int tid = threadIdx.x;
    __shared__ float paS[A_ * H_];
    __shared__ float part[A_][4];
    float* orow = out + ((size_t)(n * E_ + e)) * RO_;
    if (tid < RO_) orow[tid] = -1000000.0f;
    for (int i = tid; i < A_ * H_; i += 256) {
        const size_t o = (size_t)n * A_ * H_ + i;
        paS[i] = Pa3[o] + Pa3[PASZ + o] + Pa3[2 * PASZ + o];
    }
    __syncthreads();
    const size_t ro = ((size_t)(n * E_ + e)) * H_;
    float acc[A_] = {};
    for (int h = tid; h < H_; h += 256) {
        const float pe = Pe3[ro + h] + Pe3[PESZ + ro + h] + Pe3[2 * PESZ + ro + h] + b1[h];
        const float w2 = W2[h];
#pragma unroll
        for (int a = 0; a < A_; ++a) {
            const float x = pe + paS[a * H_ + h];
            const float g = x * 0.5f * (1.0f + erff(x * 0.70710678118654752f));
            acc[a] = fmaf(g, w2, acc[a]);
        }
    }
    const int lane = tid & 63, wv = tid >> 6;
#pragma unroll
    for (int a = 0; a < A_; ++a)
        for (int off = 32; off; off >>= 1) acc[a] += __shfl_down(acc[a], off, 64);
    if (lane == 0)
        for (int a = 0; a < A_; ++a) part[a][wv] = acc[a];
    __syncthreads();
    if (tid < A_) {
        const float s = part[tid][0] + part[tid][1] + part[tid][2] + part[tid][3] + b2[0];
        orow[arg_map[n * A_ + tid]] = s;
    }
}

extern "C" void kernel_launch(void* const* d_in, const int* in_sizes, int n_in,
                              void* d_out, int out_size, void* d_ws, size_t ws_size,
                              hipStream_t stream) {
    const float* all_emb = (const float*)d_in[0];
    const float* attn    = (const float*)d_in[1];
    const float* ent_map = (const float*)d_in[2];
    const float* argw    = (const float*)d_in[3];
    // d_in[4] is_triggers unused (reference dead code)
    const float* W1 = (const float*)d_in[5];
    const float* b1 = (const float*)d_in[6];
    const float* W2 = (const float*)d_in[7];
    const float* b2 = (const float*)d_in[8];
    const int* idxs    = (const int*)d_in[9];
    const int* arg_map = (const int*)d_in[10];
    float* out = (float*)d_out;

    float* ws = (float*)d_ws;
    // fp32 buffers (float offsets)
    float* entf = ws + 0;               // N*E*D           = 1,572,864
    float* Pe3  = ws + 1572864;         // 3*N*E*H         = 4,718,592  -> 6,291,456
    float* argE = ws + 6291456;         // N*A*D           =   110,592  -> 6,402,048
    float* wbuf = ws + 6402048;         // N*E*A           =    18,432  -> 6,420,480
    float* Pa3  = ws + 6420480;         // 3*N*A*H         =   331,776  -> 6,752,256
    // bf16 buffers (sizes in float-slots = shorts/2)
    short*          W1t     = (short*)(ws + 6752256);           // 768*4608 sh -> 8,521,728
    unsigned short* sentT   = (unsigned short*)(ws + 8521728);  // N*D*S sh    -> 9,308,160
    unsigned short* entmapT = (unsigned short*)(ws + 9308160);  // N*E*S sh    -> 9,439,232
    unsigned short* t2tbf   = (unsigned short*)(ws + 9439232);  // N*S*S sh (262,144) -> 9,570,304
    unsigned short* argEbf  = (unsigned short*)(ws + 9570304);  // N*A*D sh    -> 9,625,600
    unsigned short* u2ubf   = (unsigned short*)(ws + 9625600);  // N*A*D sh    -> 9,680,896
    unsigned short* entbf   = (unsigned short*)(ws + 9680896);  // N*E*D sh    -> 10,467,328
    unsigned short* h2hT    = (unsigned short*)(ws + 10467328); // N*D*S sh    -> 11,253,760
    unsigned short* Ah2hbf  = (unsigned short*)(ws + 11253760); // N*E*D sh    -> 12,040,192
    unsigned short* tokAbf  = (unsigned short*)(ws + 12040192); // N*E*D sh    -> 12,826,624
    unsigned short* argTbf  = (unsigned short*)(ws + 12826624); // N*A*D sh    -> 12,881,920
    // total ≈ 12.9M floats = 51.5 MB

    // stage 1: all independent transforms fused (one launch)
    stage1_k<<<GB_TOTAL, 256, 0, stream>>>(all_emb, idxs, ent_map, W1, argw, attn,
                                           sentT, entmapT, W1t, t2tbf, argE, argEbf, u2ubf);

    // stage 2a: z=0 -> h2hT = (t2t @ sent)^T ; z=1 -> ent = entmapT @ sent
    gemm_pair_k<<<dim3(D_ / 64, N_, 2), 256, 0, stream>>>(t2tbf, entmapT, sentT, entf, entbf, h2hT);

    // stage 2b: Ah2h = entmapT @ h2h  +  wbuf = transform(ent @ argE^T)
    gemm2_k<<<208, 256, 0, stream>>>(entmapT, h2hT, entbf, argEbf, Ah2hbf, wbuf);

    // stage 3: tokA + argT (both consume wbuf)
    post_k<<<N_ * E_ + N_ * A_, 256, 0, stream>>>(wbuf, argE, entf, tokAbf, argTbf);

    // stage 4: MLP layer 1, K-split by segment into disjoint partials (648 blocks, no atomics)
    // W1 row blocks: [ent 0 | argE 768 | tokA 1536 | Ah2h 2304 | argT 3072 | u2u 3840]
    mfma_mlp_k<<<dim3(54, H_ / 64), 256, 0, stream>>>(entbf, tokAbf, Ah2hbf, argEbf, argTbf, u2ubf, W1t, Pe3, Pa3);

    // stage 5: gelu + W2 + scatter (sums the 3 partials on read)
    score_k<<<N_ * E_, 256, 0, stream>>>(Pe3, Pa3, b1, W2, b2, arg_map, out);

    (void)in_sizes; (void)n_in; (void)out_size; (void)ws_size;
}